// Round 8
// baseline (586.118 us; speedup 1.0000x reference)
//
#include <hip/hip_runtime.h>
#include <cstdint>
#include <cfloat>

#define NN 2048
#define DD 128
#define BATCH 8
#define NSPLIT 4
#define CSPL 512         // cols per split
#define NTILES 32        // 16-col tiles per wave-job (512/16)

typedef double d4 __attribute__((ext_vector_type(4)));
typedef unsigned long long u64;

// ---- sortable u64 key: monotone fp64 bits, low 11 bits = 2047-col (validated R5-R7) ----
__device__ __forceinline__ u64 make_key(double s, int col) {
  u64 u = (u64)__double_as_longlong(s);
  const u64 m = (u64)((long long)u >> 63);
  u ^= (m | 0x8000000000000000ull);
  return (u & ~2047ull) | (u64)(2047 - col);
}

__device__ __forceinline__ u64 umax64(u64 a, u64 b) { return a > b ? a : b; }
__device__ __forceinline__ u64 umin64(u64 a, u64 b) { return a > b ? b : a; }

// merge two sorted-desc 8-lists -> kv = top-8 sorted desc (bitonic)
__device__ __forceinline__ void merge8(u64 (&kv)[8], const u64 (&ov)[8]) {
  u64 L[8];
  #pragma unroll
  for (int i = 0; i < 8; ++i) L[i] = umax64(kv[i], ov[7 - i]);
#define CX(i, j) { const u64 a = L[i], b = L[j]; L[i] = umax64(a, b); L[j] = umin64(a, b); }
  CX(0, 4) CX(1, 5) CX(2, 6) CX(3, 7)
  CX(0, 2) CX(1, 3) CX(4, 6) CX(5, 7)
  CX(0, 1) CX(2, 3) CX(4, 5) CX(6, 7)
#undef CX
  #pragma unroll
  for (int i = 0; i < 8; ++i) kv[i] = L[i];
}

// fold 4 new keys (unsorted) into kv: sort4 desc + bitonic merge with zero-pad
__device__ __forceinline__ void fold4(u64 (&kv)[8], u64 n0, u64 n1, u64 n2, u64 n3) {
  u64 nk[8];
  nk[0] = n0; nk[1] = n1; nk[2] = n2; nk[3] = n3;
  nk[4] = 0ull; nk[5] = 0ull; nk[6] = 0ull; nk[7] = 0ull;
#define CX(i, j) { const u64 a = nk[i], b = nk[j]; nk[i] = umax64(a, b); nk[j] = umin64(a, b); }
  CX(0, 1) CX(2, 3) CX(0, 2) CX(1, 3) CX(1, 2)
#undef CX
  merge8(kv, nk);
}

// ---------------- K3: fused normalize + barrier-free fp64 MFMA Gram + top-8 ----------------
// grid: 1024 blocks = 256 row-tiles (64 rows) x 4 col-splits (512 cols) -> 4 blocks/CU.
// Zero LDS, zero barriers. Gram operand trick (validated R7): mfma(a=B-col, b=A-row)
// -> lane's 4 acc regs all belong to ONE row; cols = rowof[r]. Normalization fused:
// fragments loaded as raw fp32 x, col-norms computed per tile in-wave (fp64).
__global__ __launch_bounds__(256, 4) void k_scores_topk(const float* __restrict__ x,
                                                        u64* __restrict__ cand) {
  const int tid = threadIdx.x;
  const int w = tid >> 6;
  const int l = tid & 63;
  const int q = l >> 4;          // lane-quad: owns k in [32q, 32q+32)
  const int c16 = l & 15;

  // --- runtime calibration of the f64 MFMA C/D layout (validated R3-R7) ---
  const double k0 = (l < 16) ? 1.0 : 0.0;
  d4 zac = {0.0, 0.0, 0.0, 0.0};
  const d4 dprobe_r = __builtin_amdgcn_mfma_f64_16x16x4f64(k0 * (double)(c16 + 1), k0, zac, 0, 0, 0);
  const d4 dprobe_c = __builtin_amdgcn_mfma_f64_16x16x4f64(k0, k0 * (double)(c16 + 1), zac, 0, 0, 0);
  int rowof[4];
  #pragma unroll
  for (int r = 0; r < 4; ++r) rowof[r] = (int)dprobe_r[r] - 1;   // a-dim (= column here)
  const int rof = (int)dprobe_c[0] - 1;                          // b-dim (= our row)

  const int rowblk = blockIdx.x >> 2;              // 0..255
  const int split = blockIdx.x & 3;
  const long long row0 = (long long)rowblk * 64 + 16 * w;   // wave's 16-row base
  const int b = rowblk >> 5;                       // batch
  const int c0 = split * CSPL;
  const float* Xb = x + ((long long)b * NN + c0) * DD;      // B-cols base (raw fp32)

  // ---- A fragment: row row0+c16, k in [32q,32q+32), normalized into fp64 regs ----
  double areg[32];
  {
    const float* Ap = x + (row0 + c16) * DD + 32 * q;
    double ss = 0.0;
    #pragma unroll
    for (int i = 0; i < 8; ++i) {
      const float4 f = reinterpret_cast<const float4*>(Ap)[i];
      const double d0 = (double)f.x, d1 = (double)f.y, d2 = (double)f.z, d3 = (double)f.w;
      areg[4 * i + 0] = d0; areg[4 * i + 1] = d1; areg[4 * i + 2] = d2; areg[4 * i + 3] = d3;
      ss = fma(d0, d0, fma(d1, d1, fma(d2, d2, fma(d3, d3, ss))));
    }
    ss += __shfl_xor(ss, 16, 64);
    ss += __shfl_xor(ss, 32, 64);
    double den = sqrt(ss);
    den = den > 1e-12 ? den : 1e-12;
    const double inv = 1.0 / den;
    #pragma unroll
    for (int j = 0; j < 32; ++j) areg[j] *= inv;
  }

  u64 kv[8];
  #pragma unroll
  for (int s = 0; s < 8; ++s) kv[s] = 0ull;

  // B-col fragments kept in fp32 (16 VGPR each), register double-buffered
  float4 fA[8], fB[8];
  {
    const float* p = Xb + (long long)c16 * DD + 32 * q;    // tile 0
    #pragma unroll
    for (int i = 0; i < 8; ++i) fA[i] = reinterpret_cast<const float4*>(p)[i];
  }

#define COMPUTE_TILE(FBUF, CT)                                                     \
  {                                                                                \
    double ss = 0.0;                                                               \
    _Pragma("unroll")                                                              \
    for (int i = 0; i < 8; ++i) {                                                  \
      const float4 f = FBUF[i];                                                    \
      const double d0 = (double)f.x, d1 = (double)f.y;                             \
      const double d2 = (double)f.z, d3 = (double)f.w;                             \
      ss = fma(d0, d0, fma(d1, d1, fma(d2, d2, fma(d3, d3, ss))));                 \
    }                                                                              \
    ss += __shfl_xor(ss, 16, 64);                                                  \
    ss += __shfl_xor(ss, 32, 64);                                                  \
    double den = sqrt(ss);                                                         \
    den = den > 1e-12 ? den : 1e-12;                                               \
    const double inv = 1.0 / den;                                                  \
    d4 acc = {0.0, 0.0, 0.0, 0.0};                                                 \
    _Pragma("unroll")                                                              \
    for (int i = 0; i < 8; ++i) {                                                  \
      const float4 f = FBUF[i];                                                    \
      acc = __builtin_amdgcn_mfma_f64_16x16x4f64((double)f.x * inv, areg[4 * i + 0], acc, 0, 0, 0); \
      acc = __builtin_amdgcn_mfma_f64_16x16x4f64((double)f.y * inv, areg[4 * i + 1], acc, 0, 0, 0); \
      acc = __builtin_amdgcn_mfma_f64_16x16x4f64((double)f.z * inv, areg[4 * i + 2], acc, 0, 0, 0); \
      acc = __builtin_amdgcn_mfma_f64_16x16x4f64((double)f.w * inv, areg[4 * i + 3], acc, 0, 0, 0); \
    }                                                                              \
    const int cb = c0 + 16 * (CT);                                                 \
    fold4(kv, make_key(acc[0], cb + rowof[0]), make_key(acc[1], cb + rowof[1]),    \
              make_key(acc[2], cb + rowof[2]), make_key(acc[3], cb + rowof[3]));   \
  }

  for (int ct = 0; ct < NTILES; ct += 2) {
    // prefetch tile ct+1 into fB (NTILES even -> always valid)
    {
      const float* p = Xb + (long long)(16 * (ct + 1) + c16) * DD + 32 * q;
      #pragma unroll
      for (int i = 0; i < 8; ++i) fB[i] = reinterpret_cast<const float4*>(p)[i];
    }
    COMPUTE_TILE(fA, ct)
    // prefetch tile ct+2 into fA
    if (ct + 2 < NTILES) {
      const float* p = Xb + (long long)(16 * (ct + 2) + c16) * DD + 32 * q;
      #pragma unroll
      for (int i = 0; i < 8; ++i) fA[i] = reinterpret_cast<const float4*>(p)[i];
    }
    COMPUTE_TILE(fB, ct + 1)
  }
#undef COMPUTE_TILE

  // merge the 4 lanes sharing each row (same c16 across quads)
  #pragma unroll
  for (int m = 16; m <= 32; m <<= 1) {
    u64 ov[8];
    #pragma unroll
    for (int s = 0; s < 8; ++s) ov[s] = __shfl_xor(kv[s], m, 64);
    merge8(kv, ov);
  }

  if (l < 16) {
    const long long base = ((long long)split * 16384 + row0 + rof) * 8;
    #pragma unroll
    for (int s = 0; s < 8; ++s) cand[base + s] = kv[s];
  }
}

// ---------------- K4: merge 4 splits per row, diag + symmetric scatter ----------------
__global__ __launch_bounds__(256) void k_merge(const u64* __restrict__ cand,
                                               float* __restrict__ out) {
  const long long r = (long long)blockIdx.x * 256 + threadIdx.x;  // 0..16383
  u64 kv[8];
  #pragma unroll
  for (int s = 0; s < 8; ++s) kv[s] = cand[r * 8 + s];
  #pragma unroll
  for (int sp = 1; sp < NSPLIT; ++sp) {
    u64 ov[8];
    #pragma unroll
    for (int s = 0; s < 8; ++s) ov[s] = cand[((long long)sp * 16384 + r) * 8 + s];
    merge8(kv, ov);
  }
  const int n = (int)(r & (NN - 1));
  const long long bbase = (r - n) * (long long)NN;   // b*N*N
  out[r * (long long)NN + n] = 1.0f;                 // self loop
  #pragma unroll
  for (int s = 0; s < 8; ++s) {
    const int m = 2047 - (int)(kv[s] & 2047ull);
    out[r * (long long)NN + m] = 1.0f;
    out[bbase + (long long)m * NN + n] = 1.0f;
  }
}

extern "C" void kernel_launch(void* const* d_in, const int* in_sizes, int n_in,
                              void* d_out, int out_size, void* d_ws, size_t ws_size,
                              hipStream_t stream) {
  const float* x = (const float*)d_in[0];
  float* out = (float*)d_out;
  u64* cand = (u64*)d_ws;                       // 4 x 16384 x 8 keys = 4,194,304 B

  hipMemsetAsync(d_out, 0, (size_t)out_size * sizeof(float), stream);
  hipLaunchKernelGGL(k_scores_topk, dim3(1024), dim3(256), 0, stream, x, cand);
  hipLaunchKernelGGL(k_merge, dim3(64), dim3(256), 0, stream, cand, out);
}

// Round 9
// 393.468 us; speedup vs baseline: 1.4896x; 1.4896x over previous
//
#include <hip/hip_runtime.h>
#include <cstdint>
#include <cfloat>

#define NN 2048
#define DD 128
#define BATCH 8
#define NSPLIT 4
#define CSPL 512         // cols per split
#define NTILES 32        // 16-col tiles per wave-job (512/16)

typedef double d4 __attribute__((ext_vector_type(4)));
typedef unsigned long long u64;

// ---------------- K1: fp64 L2-normalize rows ----------------
__global__ __launch_bounds__(256) void k_normalize(const float* __restrict__ x,
                                                   double* __restrict__ normed) {
  const int wave = threadIdx.x >> 6;
  const int lane = threadIdx.x & 63;
  const long long row = (long long)blockIdx.x * 4 + wave;   // 16384 rows
  float2 v = reinterpret_cast<const float2*>(x + row * DD)[lane];
  const double d0 = (double)v.x, d1 = (double)v.y;
  double s = d0 * d0 + d1 * d1;
  #pragma unroll
  for (int m = 32; m >= 1; m >>= 1) s += __shfl_xor(s, m, 64);
  double denom = sqrt(s);
  denom = denom > 1e-12 ? denom : 1e-12;
  double2 o;
  o.x = d0 / denom;
  o.y = d1 / denom;
  reinterpret_cast<double2*>(normed + row * DD)[lane] = o;
}

// ---- sortable u64 key: monotone fp64 bits, low 11 bits = 2047-col (validated R5-R8) ----
__device__ __forceinline__ u64 make_key(double s, int col) {
  u64 u = (u64)__double_as_longlong(s);
  const u64 m = (u64)((long long)u >> 63);
  u ^= (m | 0x8000000000000000ull);
  return (u & ~2047ull) | (u64)(2047 - col);
}

__device__ __forceinline__ u64 umax64(u64 a, u64 b) { return a > b ? a : b; }
__device__ __forceinline__ u64 umin64(u64 a, u64 b) { return a > b ? b : a; }

// merge two sorted-desc 8-lists -> kv = top-8 sorted desc (bitonic)
__device__ __forceinline__ void merge8(u64 (&kv)[8], const u64 (&ov)[8]) {
  u64 L[8];
  #pragma unroll
  for (int i = 0; i < 8; ++i) L[i] = umax64(kv[i], ov[7 - i]);
#define CX(i, j) { const u64 a = L[i], b = L[j]; L[i] = umax64(a, b); L[j] = umin64(a, b); }
  CX(0, 4) CX(1, 5) CX(2, 6) CX(3, 7)
  CX(0, 2) CX(1, 3) CX(4, 6) CX(5, 7)
  CX(0, 1) CX(2, 3) CX(4, 5) CX(6, 7)
#undef CX
  #pragma unroll
  for (int i = 0; i < 8; ++i) kv[i] = L[i];
}

// fold 4 new keys (unsorted) into kv: sort4 desc + bitonic merge with zero-pad
__device__ __forceinline__ void fold4(u64 (&kv)[8], u64 n0, u64 n1, u64 n2, u64 n3) {
  u64 nk[8];
  nk[0] = n0; nk[1] = n1; nk[2] = n2; nk[3] = n3;
  nk[4] = 0ull; nk[5] = 0ull; nk[6] = 0ull; nk[7] = 0ull;
#define CX(i, j) { const u64 a = nk[i], b = nk[j]; nk[i] = umax64(a, b); nk[j] = umin64(a, b); }
  CX(0, 1) CX(2, 3) CX(0, 2) CX(1, 3) CX(1, 2)
#undef CX
  merge8(kv, nk);
}

// ---------------- K3: barrier-free fp64 MFMA Gram + top-8 (R7 structure) ----------------
// grid: 1024 blocks = 256 row-tiles (64 rows) x 4 col-splits (512 cols).
// Zero LDS / zero barriers; VGPR ~120 -> 4 waves/SIMD co-resident (the R9 change).
// Gram operand trick (validated R7/R8): mfma(a=B-col frag, b=A-row frag) ->
// lane's 4 acc regs all belong to ONE row (row = lane&15 via rof), cols = rowof[r].
__global__ __launch_bounds__(256, 2) void k_scores_topk(const double* __restrict__ normed,
                                                        u64* __restrict__ cand) {
  const int tid = threadIdx.x;
  const int w = tid >> 6;
  const int l = tid & 63;
  const int q = l >> 4;          // lane-quad: owns k in [32q, 32q+32)
  const int c16 = l & 15;

  // --- runtime calibration of the f64 MFMA C/D layout (validated R3-R8) ---
  const double k0 = (l < 16) ? 1.0 : 0.0;
  d4 zac = {0.0, 0.0, 0.0, 0.0};
  const d4 dprobe_r = __builtin_amdgcn_mfma_f64_16x16x4f64(k0 * (double)(c16 + 1), k0, zac, 0, 0, 0);
  const d4 dprobe_c = __builtin_amdgcn_mfma_f64_16x16x4f64(k0, k0 * (double)(c16 + 1), zac, 0, 0, 0);
  int rowof[4];
  #pragma unroll
  for (int r = 0; r < 4; ++r) rowof[r] = (int)dprobe_r[r] - 1;   // a-dim (= column here)
  const int rof = (int)dprobe_c[0] - 1;                          // b-dim (= our row)

  const int rowblk = blockIdx.x >> 2;              // 0..255
  const int split = blockIdx.x & 3;
  const long long row0 = (long long)rowblk * 64 + 16 * w;   // wave's 16-row base
  const int b = rowblk >> 5;                       // batch
  const int c0 = split * CSPL;
  const double* Bb = normed + ((long long)b * NN + c0) * DD;

  // A-rows fragment (b-operand): lane holds row row0+c16, k in [32q,32q+32)
  double2 areg[16];
  {
    const double* Ap = normed + (row0 + c16) * DD + 32 * q;
    #pragma unroll
    for (int i = 0; i < 16; ++i) areg[i] = reinterpret_cast<const double2*>(Ap)[i];
  }

  u64 kv[8];
  #pragma unroll
  for (int s = 0; s < 8; ++s) kv[s] = 0ull;

  // B-cols fragments (a-operand), register double-buffered; same layout as areg
  double2 bregA[16], bregB[16];
  {
    const double* p = Bb + (long long)c16 * DD + 32 * q;   // tile 0
    #pragma unroll
    for (int i = 0; i < 16; ++i) bregA[i] = reinterpret_cast<const double2*>(p)[i];
  }

  for (int ct = 0; ct < NTILES; ct += 2) {
    // prefetch tile ct+1 into B (NTILES even -> always valid)
    {
      const double* p = Bb + (long long)(16 * (ct + 1) + c16) * DD + 32 * q;
      #pragma unroll
      for (int i = 0; i < 16; ++i) bregB[i] = reinterpret_cast<const double2*>(p)[i];
    }
    // compute tile ct from A
    {
      d4 acc = {0.0, 0.0, 0.0, 0.0};
      #pragma unroll
      for (int s2 = 0; s2 < 16; ++s2) {
        acc = __builtin_amdgcn_mfma_f64_16x16x4f64(bregA[s2].x, areg[s2].x, acc, 0, 0, 0);
        acc = __builtin_amdgcn_mfma_f64_16x16x4f64(bregA[s2].y, areg[s2].y, acc, 0, 0, 0);
      }
      const int cb = c0 + 16 * ct;
      fold4(kv, make_key(acc[0], cb + rowof[0]), make_key(acc[1], cb + rowof[1]),
                make_key(acc[2], cb + rowof[2]), make_key(acc[3], cb + rowof[3]));
    }
    // prefetch tile ct+2 into A
    if (ct + 2 < NTILES) {
      const double* p = Bb + (long long)(16 * (ct + 2) + c16) * DD + 32 * q;
      #pragma unroll
      for (int i = 0; i < 16; ++i) bregA[i] = reinterpret_cast<const double2*>(p)[i];
    }
    // compute tile ct+1 from B
    {
      d4 acc = {0.0, 0.0, 0.0, 0.0};
      #pragma unroll
      for (int s2 = 0; s2 < 16; ++s2) {
        acc = __builtin_amdgcn_mfma_f64_16x16x4f64(bregB[s2].x, areg[s2].x, acc, 0, 0, 0);
        acc = __builtin_amdgcn_mfma_f64_16x16x4f64(bregB[s2].y, areg[s2].y, acc, 0, 0, 0);
      }
      const int cb = c0 + 16 * (ct + 1);
      fold4(kv, make_key(acc[0], cb + rowof[0]), make_key(acc[1], cb + rowof[1]),
                make_key(acc[2], cb + rowof[2]), make_key(acc[3], cb + rowof[3]));
    }
  }

  // merge the 4 lanes sharing each row (same c16 across quads)
  #pragma unroll
  for (int m = 16; m <= 32; m <<= 1) {
    u64 ov[8];
    #pragma unroll
    for (int s = 0; s < 8; ++s) ov[s] = __shfl_xor(kv[s], m, 64);
    merge8(kv, ov);
  }

  if (l < 16) {
    const long long base = ((long long)split * 16384 + row0 + rof) * 8;
    #pragma unroll
    for (int s = 0; s < 8; ++s) cand[base + s] = kv[s];
  }
}

// ---------------- K4: merge 4 splits per row, diag + symmetric scatter ----------------
__global__ __launch_bounds__(256) void k_merge(const u64* __restrict__ cand,
                                               float* __restrict__ out) {
  const long long r = (long long)blockIdx.x * 256 + threadIdx.x;  // 0..16383
  u64 kv[8];
  #pragma unroll
  for (int s = 0; s < 8; ++s) kv[s] = cand[r * 8 + s];
  #pragma unroll
  for (int sp = 1; sp < NSPLIT; ++sp) {
    u64 ov[8];
    #pragma unroll
    for (int s = 0; s < 8; ++s) ov[s] = cand[((long long)sp * 16384 + r) * 8 + s];
    merge8(kv, ov);
  }
  const int n = (int)(r & (NN - 1));
  const long long bbase = (r - n) * (long long)NN;   // b*N*N
  out[r * (long long)NN + n] = 1.0f;                 // self loop
  #pragma unroll
  for (int s = 0; s < 8; ++s) {
    const int m = 2047 - (int)(kv[s] & 2047ull);
    out[r * (long long)NN + m] = 1.0f;
    out[bbase + (long long)m * NN + n] = 1.0f;
  }
}

extern "C" void kernel_launch(void* const* d_in, const int* in_sizes, int n_in,
                              void* d_out, int out_size, void* d_ws, size_t ws_size,
                              hipStream_t stream) {
  const float* x = (const float*)d_in[0];
  float* out = (float*)d_out;
  char* ws = (char*)d_ws;
  double* normed = (double*)ws;                 // 16,777,216 B
  u64* cand = (u64*)(ws + 16777216);            //  4,194,304 B (4 x 16384 x 8 keys)

  hipMemsetAsync(d_out, 0, (size_t)out_size * sizeof(float), stream);
  hipLaunchKernelGGL(k_normalize, dim3(BATCH * NN / 4), dim3(256), 0, stream, x, normed);
  hipLaunchKernelGGL(k_scores_topk, dim3(1024), dim3(256), 0, stream, normed, cand);
  hipLaunchKernelGGL(k_merge, dim3(64), dim3(256), 0, stream, cand, out);
}